// Round 12
// baseline (235.862 us; speedup 1.0000x reference)
//
#include <hip/hip_runtime.h>
#include <hip/hip_bf16.h>
#include <stdint.h>

typedef __hip_bfloat16 bf16;
typedef __attribute__((ext_vector_type(8))) short bf16x8;
typedef __attribute__((ext_vector_type(4))) float f32x4;
typedef __attribute__((ext_vector_type(8))) unsigned short u16x8;
typedef __attribute__((ext_vector_type(4))) unsigned short u16x4;

#define SLEN 2048
#define ED   1024
#define NB   4
#define AS1 __attribute__((address_space(1)))
#define AS3 __attribute__((address_space(3)))
#define SB0() __builtin_amdgcn_sched_barrier(0)

static __device__ __forceinline__ unsigned short f2bf(float f) {
    return __builtin_bit_cast(unsigned short, __float2bfloat16(f));
}

// ============================================================================
// gemm_core8 (MEASURED PASSING, R7): 256x128 / 512 thr, 8 waves (4Mx2N),
// 2-bank register fragment pipelining, 96KB LDS, 1 blk/CU. DO NOT MODIFY.
// ============================================================================
__device__ __forceinline__ void gemm_core8(
    const char* __restrict__ aT, int lda,
    const char* __restrict__ bT, int ldb,
    int nkt, char* sm, int tid, f32x4 (&acc)[4][4])
{
    const int lane = tid & 63, wave = tid >> 6;
    const int wm = wave >> 1, wn = wave & 1;
    const int fr = lane & 15, kc = lane >> 4;

    auto STAGE = [&](int kh, int Tn) {
        char* buf = sm + (Tn & 1) * 49152;
#pragma unroll
        for (int j = 0; j < 2; ++j) {
            int rid = j * 512 + tid;
            int row = rid >> 2, c = rid & 3;
            const char* src = aT + (size_t)row * lda + Tn * 128 + kh * 64
                            + ((c ^ ((row >> 1) & 3)) * 16);
            __builtin_amdgcn_global_load_lds(
                (const AS1 uint32_t*)src,
                (AS3 uint32_t*)(buf + kh * 16384 + (j * 512 + wave * 64) * 16),
                16, 0, 0);
        }
        {
            int row = tid >> 2, c = tid & 3;
            const char* src = bT + (size_t)row * ldb + Tn * 128 + kh * 64
                            + ((c ^ ((row >> 1) & 3)) * 16);
            __builtin_amdgcn_global_load_lds(
                (const AS1 uint32_t*)src,
                (AS3 uint32_t*)(buf + 32768 + kh * 8192 + (wave * 64) * 16),
                16, 0, 0);
        }
    };
    auto RD = [&](int T, int kh, bf16x8 (&a)[4], bf16x8 (&b)[4]) {
        const char* buf = sm + (T & 1) * 49152;
#pragma unroll
        for (int i = 0; i < 4; ++i) {
            int row = wm * 64 + i * 16 + fr;
            a[i] = *(const bf16x8*)(buf + kh * 16384 + row * 64
                                    + ((kc ^ ((row >> 1) & 3)) * 16));
        }
#pragma unroll
        for (int i = 0; i < 4; ++i) {
            int row = wn * 64 + i * 16 + fr;
            b[i] = *(const bf16x8*)(buf + 32768 + kh * 8192 + row * 64
                                    + ((kc ^ ((row >> 1) & 3)) * 16));
        }
    };
    auto MM = [&](bf16x8 (&a)[4], bf16x8 (&b)[4]) {
        __builtin_amdgcn_s_setprio(1);
#pragma unroll
        for (int i = 0; i < 4; ++i)
#pragma unroll
            for (int n = 0; n < 4; ++n)
                acc[i][n] = __builtin_amdgcn_mfma_f32_16x16x32_bf16(
                    a[i], b[n], acc[i][n], 0, 0, 0);
        __builtin_amdgcn_s_setprio(0);
    };

    STAGE(0, 0); STAGE(1, 0);
    asm volatile("s_waitcnt vmcnt(3)" ::: "memory");
    SB0();
    __builtin_amdgcn_s_barrier();

    bf16x8 aE[4], bE[4], aO[4], bO[4];
    for (int T = 0; T < nkt; ++T) {
        const bool pre = (T + 1 < nkt);
        RD(T, 0, aE, bE);
        SB0();
        if (pre) STAGE(0, T + 1);
        SB0();
        if (T > 0) {
            asm volatile("s_waitcnt lgkmcnt(8)" ::: "memory");
            SB0();
            MM(aO, bO);
        }
        if (pre) asm volatile("s_waitcnt vmcnt(3)" ::: "memory");
        else     asm volatile("s_waitcnt vmcnt(0)" ::: "memory");
        SB0();
        __builtin_amdgcn_s_barrier();
        RD(T, 1, aO, bO);
        SB0();
        if (pre) STAGE(1, T + 1);
        SB0();
        asm volatile("s_waitcnt lgkmcnt(8)" ::: "memory");
        SB0();
        MM(aE, bE);
        if (pre) asm volatile("s_waitcnt vmcnt(3)" ::: "memory");
        else     asm volatile("s_waitcnt vmcnt(0)" ::: "memory");
        SB0();
        __builtin_amdgcn_s_barrier();
    }
    asm volatile("s_waitcnt lgkmcnt(0)" ::: "memory");
    SB0();
    MM(aO, bO);
}

// ============================================================================
// gemm2p (MEASURED PASSING, R4): 128x128 / BK=64 / 256 thr (4 waves 2Mx2N),
// 2-buffer LDS 64KB -> 2 blocks/CU. One barrier per phase, counted vmcnt(4).
// DO NOT MODIFY (verbatim R4 core).
// ============================================================================
__device__ __forceinline__ void gemm2p(
    const char* __restrict__ aT, int lda,
    const char* __restrict__ bT, int ldb,
    int nkt, char* sm, int tid, f32x4 (&acc)[4][4])
{
    const int lane = tid & 63, wave = tid >> 6;
    const int wm = wave >> 1, wn = wave & 1;
    const int fr = lane & 15, kc = lane >> 4;

    auto STAGE = [&](int kh, int Tn) {
        char* base = sm + (Tn & 1) * 32768 + kh * 8192;
#pragma unroll
        for (int half = 0; half < 2; ++half) {
            const char* g = half ? bT : aT;
            const int ld = half ? ldb : lda;
            char* pb = base + half * 16384;
#pragma unroll
            for (int j = 0; j < 2; ++j) {
                int rid = j * 256 + tid;
                int row = rid >> 2, c = rid & 3;
                const char* src = g + (size_t)row * ld + Tn * 128 + kh * 64
                                + ((c ^ ((row >> 1) & 3)) * 16);
                __builtin_amdgcn_global_load_lds(
                    (const AS1 uint32_t*)src,
                    (AS3 uint32_t*)(pb + (j * 256 + wave * 64) * 16),
                    16, 0, 0);
            }
        }
    };

    STAGE(0, 0); STAGE(1, 0);
    asm volatile("s_waitcnt vmcnt(4)" ::: "memory");
    __builtin_amdgcn_sched_barrier(0);
    __builtin_amdgcn_s_barrier();

    for (int T = 0; T < nkt; ++T) {
        const bool pre = (T + 1 < nkt);
#pragma unroll
        for (int kh = 0; kh < 2; ++kh) {
            const char* buf = sm + (T & 1) * 32768 + kh * 8192;
            bf16x8 a[4], b[4];
#pragma unroll
            for (int i = 0; i < 4; ++i) {
                int row = wm * 64 + i * 16 + fr;
                a[i] = *(const bf16x8*)(buf + row * 64 + ((kc ^ ((row >> 1) & 3)) * 16));
            }
#pragma unroll
            for (int i = 0; i < 4; ++i) {
                int row = wn * 64 + i * 16 + fr;
                b[i] = *(const bf16x8*)(buf + 16384 + row * 64 + ((kc ^ ((row >> 1) & 3)) * 16));
            }
            if (pre) {
                STAGE(kh, T + 1);
                asm volatile("s_waitcnt vmcnt(4)" ::: "memory");
            } else {
                asm volatile("s_waitcnt vmcnt(0)" ::: "memory");
            }
            __builtin_amdgcn_sched_barrier(0);
            __builtin_amdgcn_s_barrier();
            asm volatile("s_waitcnt lgkmcnt(0)" ::: "memory");
            __builtin_amdgcn_sched_barrier(0);
            __builtin_amdgcn_s_setprio(1);
#pragma unroll
            for (int i = 0; i < 4; ++i)
#pragma unroll
                for (int n = 0; n < 4; ++n)
                    acc[i][n] = __builtin_amdgcn_mfma_f32_16x16x32_bf16(
                        a[i], b[n], acc[i][n], 0, 0, 0);
            __builtin_amdgcn_s_setprio(0);
        }
    }
}

// ---------------- convert fp32 -> bf16 (x and the 3 weights) ----------------
__global__ __launch_bounds__(256) void convert_to_bf16(
    const float* __restrict__ x, const float* __restrict__ wq,
    const float* __restrict__ wk, const float* __restrict__ wv,
    bf16* __restrict__ xb, bf16* __restrict__ wqb,
    bf16* __restrict__ wkb, bf16* __restrict__ wvb)
{
    long g = (long)blockIdx.x * 256 + threadIdx.x;
    const float* src; bf16* dst; long o;
    if (g < 1048576) { src = x; dst = xb; o = g * 8; }
    else {
        long g2 = g - 1048576;
        int w = (int)(g2 >> 17);
        o = (g2 & 131071) * 8;
        src = (w == 0) ? wq : (w == 1) ? wk : wv;
        dst = (w == 0) ? wqb : (w == 1) ? wkb : wvb;
    }
    float4 v0 = *(const float4*)(src + o);
    float4 v1 = *(const float4*)(src + o + 4);
    u16x8 r;
    r[0] = f2bf(v0.x); r[1] = f2bf(v0.y); r[2] = f2bf(v0.z); r[3] = f2bf(v0.w);
    r[4] = f2bf(v1.x); r[5] = f2bf(v1.y); r[6] = f2bf(v1.z); r[7] = f2bf(v1.w);
    *(u16x8*)(dst + o) = r;
}

// ---------------- fused QKV (R7 verbatim): 768 blocks, 3 exact rounds -------
__global__ __launch_bounds__(512, 2) void qkv_gemm(
    const bf16* __restrict__ xb, const bf16* __restrict__ wqb,
    const bf16* __restrict__ wkb, const bf16* __restrict__ wvb,
    bf16* __restrict__ Qb, bf16* __restrict__ Kb, bf16* __restrict__ Vt)
{
    extern __shared__ char smem[];
    int bid = blockIdx.x, tid = threadIdx.x;
    int xcd = bid & 7, i = bid >> 3;
    int tm = (xcd << 2) | (i & 3);
    int tn = i >> 2;
    const bf16* W = (tn < 8) ? wqb : (tn < 16) ? wkb : wvb;
    int tnl = tn & 7;
    f32x4 acc[4][4] = {};
    gemm_core8((const char*)(xb + (size_t)tm * 256 * ED), ED * 2,
               (const char*)(W + (size_t)tnl * 128 * ED), ED * 2,
               16, smem, tid, acc);

    int lane = tid & 63, wave = tid >> 6, wm = wave >> 1, wn = wave & 1;
    int rl = (lane >> 4) * 4, cl = lane & 15;
    if (tn < 16) {
        bf16* C = (tn < 8) ? Qb : Kb;
#pragma unroll
        for (int mf = 0; mf < 4; ++mf)
#pragma unroll
            for (int j = 0; j < 4; ++j) {
                int r = tm * 256 + wm * 64 + mf * 16 + rl + j;
#pragma unroll
                for (int nf = 0; nf < 4; ++nf) {
                    int c = tnl * 128 + wn * 64 + nf * 16 + cl;
                    C[(size_t)r * ED + c] = __float2bfloat16(acc[mf][nf][j]);
                }
            }
    } else {
#pragma unroll
        for (int mf = 0; mf < 4; ++mf)
#pragma unroll
            for (int j = 0; j < 4; ++j) {
                int r = tm * 256 + wm * 64 + mf * 16 + rl + j;
                int bb = r >> 11, s = r & 2047;
#pragma unroll
                for (int nf = 0; nf < 4; ++nf) {
                    int d = tnl * 128 + wn * 64 + nf * 16 + cl;
                    Vt[(((size_t)bb << 10) + d) * SLEN + s] = __float2bfloat16(acc[mf][nf][j]);
                }
            }
    }
}

// ---------------- scores = Q @ K^T / 32 (R7 verbatim), 256x128 tiles --------
__global__ __launch_bounds__(512, 2) void qk_gemm(
    const bf16* __restrict__ Qb, const bf16* __restrict__ Kb, float* __restrict__ Sc)
{
    extern __shared__ char smem[];
    int bx = blockIdx.x, b = blockIdx.y, tid = threadIdx.x;
    int t = (bx & 7) * 9 + (bx >> 3);            // XCD swizzle, 72 = 8*9, bijective
    int ti = 0;
    while ((ti + 1) * (ti + 2) <= t) ++ti;       // prefix(ti) = ti*(ti+1)
    int tj = t - ti * (ti + 1);
    f32x4 acc[4][4] = {};
    gemm_core8((const char*)(Qb + ((size_t)b * SLEN + ti * 256) * ED), ED * 2,
               (const char*)(Kb + ((size_t)b * SLEN + tj * 128) * ED), ED * 2,
               16, smem, tid, acc);

    float* Sb = Sc + (size_t)b * SLEN * SLEN;
    int lane = tid & 63, wave = tid >> 6, wm = wave >> 1, wn = wave & 1;
    int rl = (lane >> 4) * 4, cl = lane & 15;
#pragma unroll
    for (int mf = 0; mf < 4; ++mf)
#pragma unroll
        for (int j = 0; j < 4; ++j) {
            int r = ti * 256 + wm * 64 + mf * 16 + rl + j;
#pragma unroll
            for (int nf = 0; nf < 4; ++nf) {
                int c = tj * 128 + wn * 64 + nf * 16 + cl;
                Sb[(size_t)r * SLEN + c] = acc[mf][nf][j] * 0.03125f;
            }
        }
}

// ---------------- causal row softmax (R7 verbatim) --------------------------
__global__ __launch_bounds__(256) void softmax_rows(float* __restrict__ Sc)
{
    int q = blockIdx.x, b = blockIdx.y, tid = threadIdx.x;
    float* row = Sc + ((size_t)b * SLEN + q) * SLEN;
    int lane = tid & 63, wave = tid >> 6;
    __shared__ float red[4];

    float vals[8];
    float lmax = -3.0e38f;
#pragma unroll
    for (int r = 0; r < 2; ++r) {
        int i4 = tid + r * 256;
        if (i4 * 4 <= q) {
            float4 v = *(const float4*)(row + i4 * 4);
            vals[r * 4 + 0] = v.x; vals[r * 4 + 1] = v.y;
            vals[r * 4 + 2] = v.z; vals[r * 4 + 3] = v.w;
#pragma unroll
            for (int e = 0; e < 4; ++e) {
                int k = i4 * 4 + e;
                if (k <= q) lmax = fmaxf(lmax, vals[r * 4 + e]);
            }
        }
    }
#pragma unroll
    for (int o = 32; o > 0; o >>= 1) lmax = fmaxf(lmax, __shfl_xor(lmax, o));
    if (lane == 0) red[wave] = lmax;
    __syncthreads();
    float m = fmaxf(fmaxf(red[0], red[1]), fmaxf(red[2], red[3]));
    __syncthreads();
    float lsum = 0.f;
#pragma unroll
    for (int r = 0; r < 2; ++r) {
        int i4 = tid + r * 256;
        if (i4 * 4 <= q)
#pragma unroll
            for (int e = 0; e < 4; ++e) {
                int k = i4 * 4 + e;
                if (k <= q) lsum += __expf(vals[r * 4 + e] - m);
            }
    }
#pragma unroll
    for (int o = 32; o > 0; o >>= 1) lsum += __shfl_xor(lsum, o);
    if (lane == 0) red[wave] = lsum;
    __syncthreads();
    float inv = 1.0f / (red[0] + red[1] + red[2] + red[3]);
    unsigned short* prow = (unsigned short*)row;
#pragma unroll
    for (int r = 0; r < 2; ++r) {
        int i4 = tid + r * 256;
        u16x4 o4;
#pragma unroll
        for (int e = 0; e < 4; ++e) {
            int k = i4 * 4 + e;
            float p = (k <= q) ? __expf(vals[r * 4 + e] - m) * inv : 0.0f;
            o4[e] = f2bf(p);
        }
        *(u16x4*)(prow + i4 * 4) = o4;
    }
}

// ---------------- O = P @ V: persistent greedy over 512 longest-first tiles -
// 512 persistent gemm2p blocks (2/CU). Tile t (0..511): mq' = 15 - (t>>5)
// (descending K), nd = (t&31)>>2, b = t&3. Each tile claimed exactly once via
// global atomic counter (zeroed by hipMemsetAsync before launch) -> greedy
// LPT balance independent of dispatch order; each output tile written by one
// block (plain stores, no output races).
__global__ __launch_bounds__(256, 2) void pv_gemm(
    const bf16* __restrict__ P, const bf16* __restrict__ Vt,
    float* __restrict__ O, int* __restrict__ ctr)
{
    extern __shared__ char smem[];
    __shared__ int tsh;
    int tid = threadIdx.x;
    for (;;) {
        __syncthreads();                         // LDS + tsh reuse fence
        if (tid == 0) tsh = atomicAdd(ctr, 1);
        __syncthreads();
        int t = tsh;
        if (t >= 512) break;
        int mq = 15 - (t >> 5), sub = t & 31;
        int nd = sub >> 2, b = sub & 3;
        f32x4 acc[4][4] = {};
        int nkt = (mq + 1) * 2;                  // causal: k < (mq+1)*128
        gemm2p((const char*)P + ((size_t)b * SLEN + mq * 128) * 8192, 8192,
               (const char*)(Vt + ((size_t)b * ED + nd * 128) * SLEN), SLEN * 2,
               nkt, smem, tid, acc);

        int lane = tid & 63, wave = tid >> 6, wm = wave >> 1, wn = wave & 1;
        int rl = (lane >> 4) * 4, cl = lane & 15;
        float* Ob = O + (size_t)b * SLEN * ED;
#pragma unroll
        for (int mf = 0; mf < 4; ++mf)
#pragma unroll
            for (int j = 0; j < 4; ++j) {
                int r = mq * 128 + wm * 64 + mf * 16 + rl + j;
#pragma unroll
                for (int nf = 0; nf < 4; ++nf) {
                    int c = nd * 128 + wn * 64 + nf * 16 + cl;
                    Ob[(size_t)r * ED + c] = acc[mf][nf][j];
                }
            }
    }
}

extern "C" void kernel_launch(void* const* d_in, const int* in_sizes, int n_in,
                              void* d_out, int out_size, void* d_ws, size_t ws_size,
                              hipStream_t stream)
{
    const float* x  = (const float*)d_in[0];
    const float* wq = (const float*)d_in[1];
    const float* wk = (const float*)d_in[2];
    const float* wv = (const float*)d_in[3];
    float* out = (float*)d_out;

    char* ws = (char*)d_ws;
    bf16* xb  = (bf16*)(ws);                       // 16 MB
    bf16* wqb = (bf16*)(ws + 16777216);            // 2 MB
    bf16* wkb = (bf16*)(ws + 18874368);            // 2 MB (ctr reuses this after qkv)
    bf16* wvb = (bf16*)(ws + 20971520);            // 2 MB
    bf16* Qb  = (bf16*)(ws + 23068672);            // 16 MB
    bf16* Kb  = (bf16*)(ws + 39845888);            // 16 MB
    bf16* Vt  = (bf16*)(ws + 56623104);            // 16 MB
    float* Sc = (float*)(ws + 73400320);           // 64 MB (P bf16 aliases this)
    int*  ctr = (int*)(ws + 18874368);             // dead wkb region post-qkv

    (void)hipFuncSetAttribute((const void*)qkv_gemm,
            hipFuncAttributeMaxDynamicSharedMemorySize, 98304);
    (void)hipFuncSetAttribute((const void*)qk_gemm,
            hipFuncAttributeMaxDynamicSharedMemorySize, 98304);
    (void)hipFuncSetAttribute((const void*)pv_gemm,
            hipFuncAttributeMaxDynamicSharedMemorySize, 65536);

    convert_to_bf16<<<5632, 256, 0, stream>>>(x, wq, wk, wv, xb, wqb, wkb, wvb);
    qkv_gemm<<<768, 512, 98304, stream>>>(xb, wqb, wkb, wvb, Qb, Kb, Vt);
    qk_gemm<<<dim3(72, NB), 512, 98304, stream>>>(Qb, Kb, Sc);
    softmax_rows<<<dim3(SLEN, NB), 256, 0, stream>>>(Sc);
    (void)hipMemsetAsync(ctr, 0, sizeof(int), stream);
    pv_gemm<<<512, 256, 65536, stream>>>((const bf16*)Sc, Vt, out, ctr);
}

// Round 13
// 170.221 us; speedup vs baseline: 1.3856x; 1.3856x over previous
//
#include <hip/hip_runtime.h>
#include <hip/hip_bf16.h>
#include <stdint.h>

typedef __hip_bfloat16 bf16;
typedef __attribute__((ext_vector_type(8))) short bf16x8;
typedef __attribute__((ext_vector_type(4))) float f32x4;
typedef __attribute__((ext_vector_type(8))) unsigned short u16x8;
typedef __attribute__((ext_vector_type(4))) unsigned short u16x4;

#define SLEN 2048
#define ED   1024
#define NB   4
#define AS1 __attribute__((address_space(1)))
#define AS3 __attribute__((address_space(3)))
#define SB0() __builtin_amdgcn_sched_barrier(0)

static __device__ __forceinline__ unsigned short f2bf(float f) {
    return __builtin_bit_cast(unsigned short, __float2bfloat16(f));
}

// ============================================================================
// gemm_core256: R7's MEASURED-CORRECT cadence, scaled 256x128 -> 256x256.
// BK=64 (2 kh phases/tile), 512 thr = 8 waves (2M x 4N), wave tile 128x64
// -> per phase per wave: 12 ds_read_b128 + 32 MFMA (2.67:1, m201 ratio).
// LDS 128KB: 2 bufs x {A[2][256][32] 32KB + B[2][256][32] 32KB}.
// Cadence = R7 verbatim with counts scaled (proof identical, constants only):
//   phase (T,kh): RD(T,kh)->bank; STAGE(kh,T+1) [4 loads];
//                 lgkm(12) [24 DS outstanding, waits prev bank's 12; DS FIFO];
//                 MM(prev bank, 32 MFMA); vmcnt(4) [8 VM outstanding, waits
//                 prev phase's 4 = planes read NEXT phase]; barrier.
//   Overwrite of buf (T+1)&1 half kh: last readers (tile T-1, phase kh)
//   drained own lgkm before barrier(T-1,kh), >=2 barriers before the stage.
//   Tail: vmcnt(0) when no stage; epilogue lgkm(0) + MM(last bank).
// Swizzle (both-sides involution, 0 conflicts measured R3-R12):
//   16B chunk c of each 64B row lives at c ^ ((row>>1)&3).
// Per-SIMD per K-tile: 128 MFMA x 19.4cy = 2483 > LDS port 2304 -> MFMA-bound.
// ============================================================================
__device__ __forceinline__ void gemm_core256(
    const char* __restrict__ aT, int lda,   // A: 256 rows, k contiguous
    const char* __restrict__ bT, int ldb,   // B: 256 rows (n-major), k contig
    int nkt, char* sm, int tid, f32x4 (&acc)[8][4])
{
    const int lane = tid & 63, wave = tid >> 6;
    const int wm = wave >> 2, wn = wave & 3;        // 2M x 4N
    const int fr = lane & 15, kc = lane >> 4;

    auto STAGE = [&](int kh, int Tn) {
        char* buf = sm + (Tn & 1) * 65536;
#pragma unroll
        for (int half = 0; half < 2; ++half) {
            const char* g = half ? bT : aT;
            const int ld = half ? ldb : lda;
            char* pb = buf + half * 32768 + kh * 16384;
#pragma unroll
            for (int j = 0; j < 2; ++j) {
                int rid = j * 512 + tid;
                int row = rid >> 2, c = rid & 3;
                const char* src = g + (size_t)row * ld + Tn * 128 + kh * 64
                                + ((c ^ ((row >> 1) & 3)) * 16);
                __builtin_amdgcn_global_load_lds(
                    (const AS1 uint32_t*)src,
                    (AS3 uint32_t*)(pb + (j * 512 + wave * 64) * 16), 16, 0, 0);
            }
        }
    };
    auto RD = [&](int T, int kh, bf16x8 (&a)[8], bf16x8 (&b)[4]) {
        const char* buf = sm + (T & 1) * 65536;
        const char* pa = buf + kh * 16384;
        const char* pb = buf + 32768 + kh * 16384;
#pragma unroll
        for (int i = 0; i < 8; ++i) {
            int row = wm * 128 + i * 16 + fr;
            a[i] = *(const bf16x8*)(pa + row * 64 + ((kc ^ ((row >> 1) & 3)) * 16));
        }
#pragma unroll
        for (int n = 0; n < 4; ++n) {
            int row = wn * 64 + n * 16 + fr;
            b[n] = *(const bf16x8*)(pb + row * 64 + ((kc ^ ((row >> 1) & 3)) * 16));
        }
    };
    auto MM = [&](bf16x8 (&a)[8], bf16x8 (&b)[4]) {
        __builtin_amdgcn_s_setprio(1);
#pragma unroll
        for (int i = 0; i < 8; ++i)
#pragma unroll
            for (int n = 0; n < 4; ++n)
                acc[i][n] = __builtin_amdgcn_mfma_f32_16x16x32_bf16(
                    a[i], b[n], acc[i][n], 0, 0, 0);
        __builtin_amdgcn_s_setprio(0);
    };

    STAGE(0, 0); STAGE(1, 0);
    asm volatile("s_waitcnt vmcnt(4)" ::: "memory");
    SB0();
    __builtin_amdgcn_s_barrier();

    bf16x8 aE[8], bE[4], aO[8], bO[4];
    for (int T = 0; T < nkt; ++T) {
        const bool pre = (T + 1 < nkt);
        RD(T, 0, aE, bE);
        SB0();
        if (pre) STAGE(0, T + 1);
        SB0();
        if (T > 0) {
            asm volatile("s_waitcnt lgkmcnt(12)" ::: "memory");
            SB0();
            MM(aO, bO);
        }
        if (pre) asm volatile("s_waitcnt vmcnt(4)" ::: "memory");
        else     asm volatile("s_waitcnt vmcnt(0)" ::: "memory");
        SB0();
        __builtin_amdgcn_s_barrier();
        RD(T, 1, aO, bO);
        SB0();
        if (pre) STAGE(1, T + 1);
        SB0();
        asm volatile("s_waitcnt lgkmcnt(12)" ::: "memory");
        SB0();
        MM(aE, bE);
        if (pre) asm volatile("s_waitcnt vmcnt(4)" ::: "memory");
        else     asm volatile("s_waitcnt vmcnt(0)" ::: "memory");
        SB0();
        __builtin_amdgcn_s_barrier();
    }
    asm volatile("s_waitcnt lgkmcnt(0)" ::: "memory");
    SB0();
    MM(aO, bO);
}

// ---------------- convert fp32 -> bf16 (x and the 3 weights) ----------------
__global__ __launch_bounds__(256) void convert_to_bf16(
    const float* __restrict__ x, const float* __restrict__ wq,
    const float* __restrict__ wk, const float* __restrict__ wv,
    bf16* __restrict__ xb, bf16* __restrict__ wqb,
    bf16* __restrict__ wkb, bf16* __restrict__ wvb)
{
    long g = (long)blockIdx.x * 256 + threadIdx.x;
    const float* src; bf16* dst; long o;
    if (g < 1048576) { src = x; dst = xb; o = g * 8; }
    else {
        long g2 = g - 1048576;
        int w = (int)(g2 >> 17);
        o = (g2 & 131071) * 8;
        src = (w == 0) ? wq : (w == 1) ? wk : wv;
        dst = (w == 0) ? wqb : (w == 1) ? wkb : wvb;
    }
    float4 v0 = *(const float4*)(src + o);
    float4 v1 = *(const float4*)(src + o + 4);
    u16x8 r;
    r[0] = f2bf(v0.x); r[1] = f2bf(v0.y); r[2] = f2bf(v0.z); r[3] = f2bf(v0.w);
    r[4] = f2bf(v1.x); r[5] = f2bf(v1.y); r[6] = f2bf(v1.z); r[7] = f2bf(v1.w);
    *(u16x8*)(dst + o) = r;
}

// ---------------- fused QKV: [8192,3072] = xb @ [wq;wk;wv]^T ----------------
// 256x256 tiles: 32 tm x 12 tn = 384 blocks. XCD swizzle: each XCD owns
// 4 tm values (A slice = 2 MB, L2-resident) and sweeps tn.
__global__ __launch_bounds__(512, 2) void qkv_gemm(
    const bf16* __restrict__ xb, const bf16* __restrict__ wqb,
    const bf16* __restrict__ wkb, const bf16* __restrict__ wvb,
    bf16* __restrict__ Qb, bf16* __restrict__ Kb, bf16* __restrict__ Vt)
{
    extern __shared__ char smem[];
    int bid = blockIdx.x, tid = threadIdx.x;
    int xcd = bid & 7, i = bid >> 3;            // i in 0..47
    int tm = (xcd << 2) | (i & 3);              // 0..31
    int tn = i >> 2;                            // 0..11
    const bf16* W = (tn < 4) ? wqb : (tn < 8) ? wkb : wvb;
    int tnl = tn & 3;                           // 0..3 within each W
    f32x4 acc[8][4] = {};
    gemm_core256((const char*)(xb + (size_t)tm * 256 * ED), ED * 2,
                 (const char*)(W + (size_t)tnl * 256 * ED), ED * 2,
                 16, smem, tid, acc);

    int lane = tid & 63, wave = tid >> 6, wm = wave >> 2, wn = wave & 3;
    int rl = (lane >> 4) * 4, cl = lane & 15;
    if (tn < 8) {
        bf16* C = (tn < 4) ? Qb : Kb;
#pragma unroll
        for (int mf = 0; mf < 8; ++mf)
#pragma unroll
            for (int j = 0; j < 4; ++j) {
                int r = tm * 256 + wm * 128 + mf * 16 + rl + j;
#pragma unroll
                for (int nf = 0; nf < 4; ++nf) {
                    int c = tnl * 256 + wn * 64 + nf * 16 + cl;
                    C[(size_t)r * ED + c] = __float2bfloat16(acc[mf][nf][j]);
                }
            }
    } else {
#pragma unroll
        for (int mf = 0; mf < 8; ++mf)
#pragma unroll
            for (int j = 0; j < 4; ++j) {
                int r = tm * 256 + wm * 128 + mf * 16 + rl + j;
                int bb = r >> 11, s = r & 2047;
#pragma unroll
                for (int nf = 0; nf < 4; ++nf) {
                    int d = tnl * 256 + wn * 64 + nf * 16 + cl;
                    Vt[(((size_t)bb << 10) + d) * SLEN + s] = __float2bfloat16(acc[mf][nf][j]);
                }
            }
    }
}

// ---------------- scores = Q @ K^T / 32, lower-tri 256^2 tiles --------------
// tiles (ti,tj) with tj <= ti: 36/batch -> grid (36, NB) = 144 blocks, 1 round.
__global__ __launch_bounds__(512, 2) void qk_gemm(
    const bf16* __restrict__ Qb, const bf16* __restrict__ Kb, float* __restrict__ Sc)
{
    extern __shared__ char smem[];
    int t = blockIdx.x, b = blockIdx.y, tid = threadIdx.x;
    int ti = 0;
    while ((ti + 1) * (ti + 2) / 2 <= t) ++ti;   // triangular decode, ti<=7
    int tj = t - ti * (ti + 1) / 2;
    f32x4 acc[8][4] = {};
    gemm_core256((const char*)(Qb + ((size_t)b * SLEN + ti * 256) * ED), ED * 2,
                 (const char*)(Kb + ((size_t)b * SLEN + tj * 256) * ED), ED * 2,
                 16, smem, tid, acc);

    float* Sb = Sc + (size_t)b * SLEN * SLEN;
    int lane = tid & 63, wave = tid >> 6, wm = wave >> 2, wn = wave & 3;
    int rl = (lane >> 4) * 4, cl = lane & 15;
#pragma unroll
    for (int mf = 0; mf < 8; ++mf)
#pragma unroll
        for (int j = 0; j < 4; ++j) {
            int r = ti * 256 + wm * 128 + mf * 16 + rl + j;
#pragma unroll
            for (int nf = 0; nf < 4; ++nf) {
                int c = tj * 256 + wn * 64 + nf * 16 + cl;
                Sb[(size_t)r * SLEN + c] = acc[mf][nf][j] * 0.03125f;
            }
        }
}

// ---------------- causal row softmax (R7 verbatim) --------------------------
__global__ __launch_bounds__(256) void softmax_rows(float* __restrict__ Sc)
{
    int q = blockIdx.x, b = blockIdx.y, tid = threadIdx.x;
    float* row = Sc + ((size_t)b * SLEN + q) * SLEN;
    int lane = tid & 63, wave = tid >> 6;
    __shared__ float red[4];

    float vals[8];
    float lmax = -3.0e38f;
#pragma unroll
    for (int r = 0; r < 2; ++r) {
        int i4 = tid + r * 256;
        if (i4 * 4 <= q) {
            float4 v = *(const float4*)(row + i4 * 4);
            vals[r * 4 + 0] = v.x; vals[r * 4 + 1] = v.y;
            vals[r * 4 + 2] = v.z; vals[r * 4 + 3] = v.w;
#pragma unroll
            for (int e = 0; e < 4; ++e) {
                int k = i4 * 4 + e;
                if (k <= q) lmax = fmaxf(lmax, vals[r * 4 + e]);
            }
        }
    }
#pragma unroll
    for (int o = 32; o > 0; o >>= 1) lmax = fmaxf(lmax, __shfl_xor(lmax, o));
    if (lane == 0) red[wave] = lmax;
    __syncthreads();
    float m = fmaxf(fmaxf(red[0], red[1]), fmaxf(red[2], red[3]));
    __syncthreads();
    float lsum = 0.f;
#pragma unroll
    for (int r = 0; r < 2; ++r) {
        int i4 = tid + r * 256;
        if (i4 * 4 <= q)
#pragma unroll
            for (int e = 0; e < 4; ++e) {
                int k = i4 * 4 + e;
                if (k <= q) lsum += __expf(vals[r * 4 + e] - m);
            }
    }
#pragma unroll
    for (int o = 32; o > 0; o >>= 1) lsum += __shfl_xor(lsum, o);
    if (lane == 0) red[wave] = lsum;
    __syncthreads();
    float inv = 1.0f / (red[0] + red[1] + red[2] + red[3]);
    unsigned short* prow = (unsigned short*)row;
#pragma unroll
    for (int r = 0; r < 2; ++r) {
        int i4 = tid + r * 256;
        u16x4 o4;
#pragma unroll
        for (int e = 0; e < 4; ++e) {
            int k = i4 * 4 + e;
            float p = (k <= q) ? __expf(vals[r * 4 + e] - m) * inv : 0.0f;
            o4[e] = f2bf(p);
        }
        *(u16x4*)(prow + i4 * 4) = o4;
    }
}

// ---------------- O = P @ V (P bf16 ld 4096 elems; Vt [b][d][s]) ------------
// 256x256 tiles: 8 mq x 4 nd x 4 b = 128 blocks, all resident; longest first.
__global__ __launch_bounds__(512, 2) void pv_gemm(
    const bf16* __restrict__ P, const bf16* __restrict__ Vt, float* __restrict__ O)
{
    extern __shared__ char smem[];
    int mq = 7 - blockIdx.x, nd = blockIdx.y, b = blockIdx.z, tid = threadIdx.x;
    f32x4 acc[8][4] = {};
    int nkt = (mq + 1) * 4;                      // causal: k < (mq+1)*256
    gemm_core256((const char*)P + ((size_t)b * SLEN + mq * 256) * 8192, 8192,
                 (const char*)(Vt + ((size_t)b * ED + nd * 256) * SLEN), SLEN * 2,
                 nkt, smem, tid, acc);

    int lane = tid & 63, wave = tid >> 6, wm = wave >> 2, wn = wave & 3;
    int rl = (lane >> 4) * 4, cl = lane & 15;
    float* Ob = O + (size_t)b * SLEN * ED;
#pragma unroll
    for (int mf = 0; mf < 8; ++mf)
#pragma unroll
        for (int j = 0; j < 4; ++j) {
            int r = mq * 256 + wm * 128 + mf * 16 + rl + j;
#pragma unroll
            for (int nf = 0; nf < 4; ++nf) {
                int c = nd * 256 + wn * 64 + nf * 16 + cl;
                Ob[(size_t)r * ED + c] = acc[mf][nf][j];
            }
        }
}

extern "C" void kernel_launch(void* const* d_in, const int* in_sizes, int n_in,
                              void* d_out, int out_size, void* d_ws, size_t ws_size,
                              hipStream_t stream)
{
    const float* x  = (const float*)d_in[0];
    const float* wq = (const float*)d_in[1];
    const float* wk = (const float*)d_in[2];
    const float* wv = (const float*)d_in[3];
    float* out = (float*)d_out;

    char* ws = (char*)d_ws;
    bf16* xb  = (bf16*)(ws);                       // 16 MB
    bf16* wqb = (bf16*)(ws + 16777216);            // 2 MB
    bf16* wkb = (bf16*)(ws + 18874368);            // 2 MB
    bf16* wvb = (bf16*)(ws + 20971520);            // 2 MB
    bf16* Qb  = (bf16*)(ws + 23068672);            // 16 MB
    bf16* Kb  = (bf16*)(ws + 39845888);            // 16 MB
    bf16* Vt  = (bf16*)(ws + 56623104);            // 16 MB
    float* Sc = (float*)(ws + 73400320);           // 64 MB (P bf16 aliases this)

    (void)hipFuncSetAttribute((const void*)qkv_gemm,
            hipFuncAttributeMaxDynamicSharedMemorySize, 131072);
    (void)hipFuncSetAttribute((const void*)qk_gemm,
            hipFuncAttributeMaxDynamicSharedMemorySize, 131072);
    (void)hipFuncSetAttribute((const void*)pv_gemm,
            hipFuncAttributeMaxDynamicSharedMemorySize, 131072);

    convert_to_bf16<<<5632, 256, 0, stream>>>(x, wq, wk, wv, xb, wqb, wkb, wvb);
    qkv_gemm<<<384, 512, 131072, stream>>>(xb, wqb, wkb, wvb, Qb, Kb, Vt);
    qk_gemm<<<dim3(36, NB), 512, 131072, stream>>>(Qb, Kb, Sc);
    softmax_rows<<<dim3(SLEN, NB), 256, 0, stream>>>(Sc);
    pv_gemm<<<dim3(8, 4, NB), 512, 131072, stream>>>((const bf16*)Sc, Vt, out);
}

// Round 14
// 163.765 us; speedup vs baseline: 1.4403x; 1.0394x over previous
//
#include <hip/hip_runtime.h>
#include <hip/hip_bf16.h>
#include <stdint.h>

typedef __hip_bfloat16 bf16;
typedef __attribute__((ext_vector_type(8))) short bf16x8;
typedef __attribute__((ext_vector_type(4))) float f32x4;
typedef __attribute__((ext_vector_type(8))) unsigned short u16x8;
typedef __attribute__((ext_vector_type(4))) unsigned short u16x4;

#define SLEN 2048
#define ED   1024
#define NB   4
#define AS1 __attribute__((address_space(1)))
#define AS3 __attribute__((address_space(3)))
#define SB0() __builtin_amdgcn_sched_barrier(0)

static __device__ __forceinline__ unsigned short f2bf(float f) {
    return __builtin_bit_cast(unsigned short, __float2bfloat16(f));
}

// ============================================================================
// gemm8p: m201-style 8-phase 256x256 / BK=64 / 512-thr core on the
// correctness-proven LDS atoms of R13 (which PASSED; only its phase
// structure was slow). 8 waves (2M x 4N), wave tile 128x64.
// LDS 128KB: buf d = (T&1)*65536; A-kh unit at kh*16384 ([256][32] elems),
// B-kh unit at 32768 + kh*16384. Swizzle: chunk c of each 64B row at
// c ^ ((row>>1)&3) (involution, both sides; 0 bank conflicts R3-R13).
//
// Phases per tile T (nh = n-half of the wave's 64 cols):
//  ph1 (k0,nh0): RDA(k0)8 + RDB2; stage B-k1(T+1)
//  ph2 (k0,nh1): RDB2 (A frags reused);  stage A-k0(T+2)
//  ph3 (k1,nh0): RDA(k1)8 + RDB2;        stage B-k0(T+2)
//  ph4 (k1,nh1): RDB2;                   stage A-k1(T+2); vmcnt
//  each phase: [reads; stage] SB0 barrier lgkm(0) SB0 {16 MFMA, setprio} SB0 barrier
//
// vmcnt(6) at ph4 only (tail: vmcnt(0) for T >= nkt-2):
//  queue at ph4 = leftovers(<=6: A-k0,B-k0,A-k1 of T+1) + 8 new
//  -> wait<=6 retires all leftovers + B-k1(T+1) => tile T+1 fully in LDS
//  before any wave crosses ph4's barrier. (Per-wave count + barrier =>
//  cross-wave complete.)
// Overwrite safety (1-phase lag, each via reader's lgkm(0)+barrier):
//  A-k0(T+2)@ph2 overwrites A-k0(T), last read ph1; B-k0(T+2)@ph3 over
//  B-k0(T) last read ph2; A-k1(T+2)@ph4 over A-k1(T) last read ph3;
//  B-k1(T+1)@ph1 (other buffer) over B-k1(T-1), last read (T-1)ph4.
// Prologue stages 7 units [tile0 x4 + A-k0,B-k0,A-k1 of tile1], vmcnt(6)
// retires tile 0. nkt must be >= 2 (all callers use >= 16).
// ============================================================================
__device__ __forceinline__ void gemm8p(
    const char* __restrict__ aT, int lda,   // A: 256 rows, k contiguous
    const char* __restrict__ bT, int ldb,   // B: 256 rows (n-major), k contig
    int nkt, char* sm, int tid, f32x4 (&acc)[8][4])
{
    const int lane = tid & 63, wave = tid >> 6;
    const int wm = wave >> 2, wn = wave & 3;        // 2M x 4N
    const int fr = lane & 15, kc = lane >> 4;

    // stage one 16KB unit (2 loads/thread). isB selects A/B, kh the k-half.
    auto SU = [&](int isB, int kh, int Tn) {
        char* dst = sm + (Tn & 1) * 65536 + isB * 32768 + kh * 16384;
        const char* g = isB ? bT : aT;
        const int ld = isB ? ldb : lda;
#pragma unroll
        for (int j = 0; j < 2; ++j) {
            int rid = j * 512 + tid;
            int row = rid >> 2, c = rid & 3;
            const char* src = g + (size_t)row * ld + Tn * 128 + kh * 64
                            + ((c ^ ((row >> 1) & 3)) * 16);
            __builtin_amdgcn_global_load_lds(
                (const AS1 uint32_t*)src,
                (AS3 uint32_t*)(dst + (j * 512 + wave * 64) * 16), 16, 0, 0);
        }
    };
    auto RDA = [&](int T, int kh, bf16x8 (&a)[8]) {
        const char* pa = sm + (T & 1) * 65536 + kh * 16384;
#pragma unroll
        for (int i = 0; i < 8; ++i) {
            int row = wm * 128 + i * 16 + fr;
            a[i] = *(const bf16x8*)(pa + row * 64 + ((kc ^ ((row >> 1) & 3)) * 16));
        }
    };
    auto RDB = [&](int T, int kh, int nh, bf16x8 (&b)[2]) {
        const char* pb = sm + (T & 1) * 65536 + 32768 + kh * 16384;
#pragma unroll
        for (int n = 0; n < 2; ++n) {
            int row = wn * 64 + nh * 32 + n * 16 + fr;
            b[n] = *(const bf16x8*)(pb + row * 64 + ((kc ^ ((row >> 1) & 3)) * 16));
        }
    };
    auto MM = [&](bf16x8 (&a)[8], bf16x8 (&b)[2], int nh) {
        __builtin_amdgcn_s_setprio(1);
#pragma unroll
        for (int i = 0; i < 8; ++i)
#pragma unroll
            for (int n = 0; n < 2; ++n)
                acc[i][nh * 2 + n] = __builtin_amdgcn_mfma_f32_16x16x32_bf16(
                    a[i], b[n], acc[i][nh * 2 + n], 0, 0, 0);
        __builtin_amdgcn_s_setprio(0);
    };

    // prologue: tile0 (A0,B0,A1,B1) + tile1 (A0,B0,A1); vmcnt(6) -> tile0 ready
    SU(0, 0, 0); SU(1, 0, 0); SU(0, 1, 0); SU(1, 1, 0);
    SU(0, 0, 1); SU(1, 0, 1); SU(0, 1, 1);
    asm volatile("s_waitcnt vmcnt(6)" ::: "memory");
    SB0();
    __builtin_amdgcn_s_barrier();

    for (int T = 0; T < nkt; ++T) {
        const bool p1 = (T + 1 < nkt), p2 = (T + 2 < nkt);
        bf16x8 a[8], b[2];
        // ---- ph1: (k0, nh0) ----
        RDA(T, 0, a); RDB(T, 0, 0, b);
        if (p1) SU(1, 1, T + 1);                 // B-k1(T+1)
        SB0(); __builtin_amdgcn_s_barrier();
        asm volatile("s_waitcnt lgkmcnt(0)" ::: "memory");
        SB0();
        MM(a, b, 0);
        SB0(); __builtin_amdgcn_s_barrier();
        // ---- ph2: (k0, nh1) ----
        RDB(T, 0, 1, b);
        if (p2) SU(0, 0, T + 2);                 // A-k0(T+2)
        SB0(); __builtin_amdgcn_s_barrier();
        asm volatile("s_waitcnt lgkmcnt(0)" ::: "memory");
        SB0();
        MM(a, b, 1);
        SB0(); __builtin_amdgcn_s_barrier();
        // ---- ph3: (k1, nh0) ----
        RDA(T, 1, a); RDB(T, 1, 0, b);
        if (p2) SU(1, 0, T + 2);                 // B-k0(T+2)
        SB0(); __builtin_amdgcn_s_barrier();
        asm volatile("s_waitcnt lgkmcnt(0)" ::: "memory");
        SB0();
        MM(a, b, 0);
        SB0(); __builtin_amdgcn_s_barrier();
        // ---- ph4: (k1, nh1) ----
        RDB(T, 1, 1, b);
        if (p2) SU(0, 1, T + 2);                 // A-k1(T+2)
        if (T < nkt - 2) asm volatile("s_waitcnt vmcnt(6)" ::: "memory");
        else             asm volatile("s_waitcnt vmcnt(0)" ::: "memory");
        SB0(); __builtin_amdgcn_s_barrier();
        asm volatile("s_waitcnt lgkmcnt(0)" ::: "memory");
        SB0();
        MM(a, b, 1);
        SB0(); __builtin_amdgcn_s_barrier();
    }
}

// ============================================================================
// gemm_core8 (MEASURED PASSING, R7): 256x128 / 512 thr. Used by pv. DO NOT
// MODIFY.
// ============================================================================
__device__ __forceinline__ void gemm_core8(
    const char* __restrict__ aT, int lda,
    const char* __restrict__ bT, int ldb,
    int nkt, char* sm, int tid, f32x4 (&acc)[4][4])
{
    const int lane = tid & 63, wave = tid >> 6;
    const int wm = wave >> 1, wn = wave & 1;
    const int fr = lane & 15, kc = lane >> 4;

    auto STAGE = [&](int kh, int Tn) {
        char* buf = sm + (Tn & 1) * 49152;
#pragma unroll
        for (int j = 0; j < 2; ++j) {
            int rid = j * 512 + tid;
            int row = rid >> 2, c = rid & 3;
            const char* src = aT + (size_t)row * lda + Tn * 128 + kh * 64
                            + ((c ^ ((row >> 1) & 3)) * 16);
            __builtin_amdgcn_global_load_lds(
                (const AS1 uint32_t*)src,
                (AS3 uint32_t*)(buf + kh * 16384 + (j * 512 + wave * 64) * 16),
                16, 0, 0);
        }
        {
            int row = tid >> 2, c = tid & 3;
            const char* src = bT + (size_t)row * ldb + Tn * 128 + kh * 64
                            + ((c ^ ((row >> 1) & 3)) * 16);
            __builtin_amdgcn_global_load_lds(
                (const AS1 uint32_t*)src,
                (AS3 uint32_t*)(buf + 32768 + kh * 8192 + (wave * 64) * 16),
                16, 0, 0);
        }
    };
    auto RD = [&](int T, int kh, bf16x8 (&a)[4], bf16x8 (&b)[4]) {
        const char* buf = sm + (T & 1) * 49152;
#pragma unroll
        for (int i = 0; i < 4; ++i) {
            int row = wm * 64 + i * 16 + fr;
            a[i] = *(const bf16x8*)(buf + kh * 16384 + row * 64
                                    + ((kc ^ ((row >> 1) & 3)) * 16));
        }
#pragma unroll
        for (int i = 0; i < 4; ++i) {
            int row = wn * 64 + i * 16 + fr;
            b[i] = *(const bf16x8*)(buf + 32768 + kh * 8192 + row * 64
                                    + ((kc ^ ((row >> 1) & 3)) * 16));
        }
    };
    auto MM = [&](bf16x8 (&a)[4], bf16x8 (&b)[4]) {
        __builtin_amdgcn_s_setprio(1);
#pragma unroll
        for (int i = 0; i < 4; ++i)
#pragma unroll
            for (int n = 0; n < 4; ++n)
                acc[i][n] = __builtin_amdgcn_mfma_f32_16x16x32_bf16(
                    a[i], b[n], acc[i][n], 0, 0, 0);
        __builtin_amdgcn_s_setprio(0);
    };

    STAGE(0, 0); STAGE(1, 0);
    asm volatile("s_waitcnt vmcnt(3)" ::: "memory");
    SB0();
    __builtin_amdgcn_s_barrier();

    bf16x8 aE[4], bE[4], aO[4], bO[4];
    for (int T = 0; T < nkt; ++T) {
        const bool pre = (T + 1 < nkt);
        RD(T, 0, aE, bE);
        SB0();
        if (pre) STAGE(0, T + 1);
        SB0();
        if (T > 0) {
            asm volatile("s_waitcnt lgkmcnt(8)" ::: "memory");
            SB0();
            MM(aO, bO);
        }
        if (pre) asm volatile("s_waitcnt vmcnt(3)" ::: "memory");
        else     asm volatile("s_waitcnt vmcnt(0)" ::: "memory");
        SB0();
        __builtin_amdgcn_s_barrier();
        RD(T, 1, aO, bO);
        SB0();
        if (pre) STAGE(1, T + 1);
        SB0();
        asm volatile("s_waitcnt lgkmcnt(8)" ::: "memory");
        SB0();
        MM(aE, bE);
        if (pre) asm volatile("s_waitcnt vmcnt(3)" ::: "memory");
        else     asm volatile("s_waitcnt vmcnt(0)" ::: "memory");
        SB0();
        __builtin_amdgcn_s_barrier();
    }
    asm volatile("s_waitcnt lgkmcnt(0)" ::: "memory");
    SB0();
    MM(aO, bO);
}

// ---------------- convert fp32 -> bf16 (x and the 3 weights) ----------------
__global__ __launch_bounds__(256) void convert_to_bf16(
    const float* __restrict__ x, const float* __restrict__ wq,
    const float* __restrict__ wk, const float* __restrict__ wv,
    bf16* __restrict__ xb, bf16* __restrict__ wqb,
    bf16* __restrict__ wkb, bf16* __restrict__ wvb)
{
    long g = (long)blockIdx.x * 256 + threadIdx.x;
    const float* src; bf16* dst; long o;
    if (g < 1048576) { src = x; dst = xb; o = g * 8; }
    else {
        long g2 = g - 1048576;
        int w = (int)(g2 >> 17);
        o = (g2 & 131071) * 8;
        src = (w == 0) ? wq : (w == 1) ? wk : wv;
        dst = (w == 0) ? wqb : (w == 1) ? wkb : wvb;
    }
    float4 v0 = *(const float4*)(src + o);
    float4 v1 = *(const float4*)(src + o + 4);
    u16x8 r;
    r[0] = f2bf(v0.x); r[1] = f2bf(v0.y); r[2] = f2bf(v0.z); r[3] = f2bf(v0.w);
    r[4] = f2bf(v1.x); r[5] = f2bf(v1.y); r[6] = f2bf(v1.z); r[7] = f2bf(v1.w);
    *(u16x8*)(dst + o) = r;
}

// ---------------- fused QKV: 256^2 tiles, 384 blocks, 8-phase core ----------
// Decode + epilogue verbatim from R13 (measured passing).
__global__ __launch_bounds__(512, 2) void qkv_gemm(
    const bf16* __restrict__ xb, const bf16* __restrict__ wqb,
    const bf16* __restrict__ wkb, const bf16* __restrict__ wvb,
    bf16* __restrict__ Qb, bf16* __restrict__ Kb, bf16* __restrict__ Vt)
{
    extern __shared__ char smem[];
    int bid = blockIdx.x, tid = threadIdx.x;
    int xcd = bid & 7, i = bid >> 3;            // i in 0..47
    int tm = (xcd << 2) | (i & 3);              // 0..31
    int tn = i >> 2;                            // 0..11
    const bf16* W = (tn < 4) ? wqb : (tn < 8) ? wkb : wvb;
    int tnl = tn & 3;
    f32x4 acc[8][4] = {};
    gemm8p((const char*)(xb + (size_t)tm * 256 * ED), ED * 2,
           (const char*)(W + (size_t)tnl * 256 * ED), ED * 2,
           16, smem, tid, acc);

    int lane = tid & 63, wave = tid >> 6, wm = wave >> 2, wn = wave & 3;
    int rl = (lane >> 4) * 4, cl = lane & 15;
    if (tn < 8) {
        bf16* C = (tn < 4) ? Qb : Kb;
#pragma unroll
        for (int mf = 0; mf < 8; ++mf)
#pragma unroll
            for (int j = 0; j < 4; ++j) {
                int r = tm * 256 + wm * 128 + mf * 16 + rl + j;
#pragma unroll
                for (int nf = 0; nf < 4; ++nf) {
                    int c = tnl * 256 + wn * 64 + nf * 16 + cl;
                    C[(size_t)r * ED + c] = __float2bfloat16(acc[mf][nf][j]);
                }
            }
    } else {
#pragma unroll
        for (int mf = 0; mf < 8; ++mf)
#pragma unroll
            for (int j = 0; j < 4; ++j) {
                int r = tm * 256 + wm * 128 + mf * 16 + rl + j;
                int bb = r >> 11, s = r & 2047;
#pragma unroll
                for (int nf = 0; nf < 4; ++nf) {
                    int d = tnl * 256 + wn * 64 + nf * 16 + cl;
                    Vt[(((size_t)bb << 10) + d) * SLEN + s] = __float2bfloat16(acc[mf][nf][j]);
                }
            }
    }
}

// ---------------- scores = Q @ K^T / 32, lower-tri 256^2 tiles --------------
// 36 tiles x 4 batches = 144 blocks (one round). Decode/epilogue = R13
// (measured passing), core swapped to gemm8p.
__global__ __launch_bounds__(512, 2) void qk_gemm(
    const bf16* __restrict__ Qb, const bf16* __restrict__ Kb, float* __restrict__ Sc)
{
    extern __shared__ char smem[];
    int t = blockIdx.x, b = blockIdx.y, tid = threadIdx.x;
    int ti = 0;
    while ((ti + 1) * (ti + 2) / 2 <= t) ++ti;   // triangular decode, ti<=7
    int tj = t - ti * (ti + 1) / 2;
    f32x4 acc[8][4] = {};
    gemm8p((const char*)(Qb + ((size_t)b * SLEN + ti * 256) * ED), ED * 2,
           (const char*)(Kb + ((size_t)b * SLEN + tj * 256) * ED), ED * 2,
           16, smem, tid, acc);

    float* Sb = Sc + (size_t)b * SLEN * SLEN;
    int lane = tid & 63, wave = tid >> 6, wm = wave >> 2, wn = wave & 3;
    int rl = (lane >> 4) * 4, cl = lane & 15;
#pragma unroll
    for (int mf = 0; mf < 8; ++mf)
#pragma unroll
        for (int j = 0; j < 4; ++j) {
            int r = ti * 256 + wm * 128 + mf * 16 + rl + j;
#pragma unroll
            for (int nf = 0; nf < 4; ++nf) {
                int c = tj * 256 + wn * 64 + nf * 16 + cl;
                Sb[(size_t)r * SLEN + c] = acc[mf][nf][j] * 0.03125f;
            }
        }
}

// ---------------- causal row softmax (R7 verbatim) --------------------------
__global__ __launch_bounds__(256) void softmax_rows(float* __restrict__ Sc)
{
    int q = blockIdx.x, b = blockIdx.y, tid = threadIdx.x;
    float* row = Sc + ((size_t)b * SLEN + q) * SLEN;
    int lane = tid & 63, wave = tid >> 6;
    __shared__ float red[4];

    float vals[8];
    float lmax = -3.0e38f;
#pragma unroll
    for (int r = 0; r < 2; ++r) {
        int i4 = tid + r * 256;
        if (i4 * 4 <= q) {
            float4 v = *(const float4*)(row + i4 * 4);
            vals[r * 4 + 0] = v.x; vals[r * 4 + 1] = v.y;
            vals[r * 4 + 2] = v.z; vals[r * 4 + 3] = v.w;
#pragma unroll
            for (int e = 0; e < 4; ++e) {
                int k = i4 * 4 + e;
                if (k <= q) lmax = fmaxf(lmax, vals[r * 4 + e]);
            }
        }
    }
#pragma unroll
    for (int o = 32; o > 0; o >>= 1) lmax = fmaxf(lmax, __shfl_xor(lmax, o));
    if (lane == 0) red[wave] = lmax;
    __syncthreads();
    float m = fmaxf(fmaxf(red[0], red[1]), fmaxf(red[2], red[3]));
    __syncthreads();
    float lsum = 0.f;
#pragma unroll
    for (int r = 0; r < 2; ++r) {
        int i4 = tid + r * 256;
        if (i4 * 4 <= q)
#pragma unroll
            for (int e = 0; e < 4; ++e) {
                int k = i4 * 4 + e;
                if (k <= q) lsum += __expf(vals[r * 4 + e] - m);
            }
    }
#pragma unroll
    for (int o = 32; o > 0; o >>= 1) lsum += __shfl_xor(lsum, o);
    if (lane == 0) red[wave] = lsum;
    __syncthreads();
    float inv = 1.0f / (red[0] + red[1] + red[2] + red[3]);
    unsigned short* prow = (unsigned short*)row;
#pragma unroll
    for (int r = 0; r < 2; ++r) {
        int i4 = tid + r * 256;
        u16x4 o4;
#pragma unroll
        for (int e = 0; e < 4; ++e) {
            int k = i4 * 4 + e;
            float p = (k <= q) ? __expf(vals[r * 4 + e] - m) * inv : 0.0f;
            o4[e] = f2bf(p);
        }
        *(u16x4*)(prow + i4 * 4) = o4;
    }
}

// ---------------- O = P @ V (R7 verbatim): 256x128 tiles, 256 blocks --------
__global__ __launch_bounds__(512, 2) void pv_gemm(
    const bf16* __restrict__ P, const bf16* __restrict__ Vt, float* __restrict__ O)
{
    extern __shared__ char smem[];
    int mq = 7 - blockIdx.x, nd = blockIdx.y, b = blockIdx.z, tid = threadIdx.x;
    f32x4 acc[4][4] = {};
    int nkt = (mq + 1) * 4;                      // causal: k < (mq+1)*256
    gemm_core8((const char*)P + ((size_t)b * SLEN + mq * 256) * 8192, 8192,
               (const char*)(Vt + ((size_t)b * ED + nd * 128) * SLEN), SLEN * 2,
               nkt, smem, tid, acc);

    int lane = tid & 63, wave = tid >> 6, wm = wave >> 1, wn = wave & 1;
    int rl = (lane >> 4) * 4, cl = lane & 15;
    float* Ob = O + (size_t)b * SLEN * ED;
#pragma unroll
    for (int mf = 0; mf < 4; ++mf)
#pragma unroll
        for (int j = 0; j < 4; ++j) {
            int r = mq * 256 + wm * 64 + mf * 16 + rl + j;
#pragma unroll
            for (int nf = 0; nf < 4; ++nf) {
                int c = nd * 128 + wn * 64 + nf * 16 + cl;
                Ob[(size_t)r * ED + c] = acc[mf][nf][j];
            }
        }
}

extern "C" void kernel_launch(void* const* d_in, const int* in_sizes, int n_in,
                              void* d_out, int out_size, void* d_ws, size_t ws_size,
                              hipStream_t stream)
{
    const float* x  = (const float*)d_in[0];
    const float* wq = (const float*)d_in[1];
    const float* wk = (const float*)d_in[2];
    const float* wv = (const float*)d_in[3];
    float* out = (float*)d_out;

    char* ws = (char*)d_ws;
    bf16* xb  = (bf16*)(ws);                       // 16 MB
    bf16* wqb = (bf16*)(ws + 16777216);            // 2 MB
    bf16* wkb = (bf16*)(ws + 18874368);            // 2 MB
    bf16* wvb = (bf16*)(ws + 20971520);            // 2 MB
    bf16* Qb  = (bf16*)(ws + 23068672);            // 16 MB
    bf16* Kb  = (bf16*)(ws + 39845888);            // 16 MB
    bf16* Vt  = (bf16*)(ws + 56623104);            // 16 MB
    float* Sc = (float*)(ws + 73400320);           // 64 MB (P bf16 aliases this)

    (void)hipFuncSetAttribute((const void*)qkv_gemm,
            hipFuncAttributeMaxDynamicSharedMemorySize, 131072);
    (void)hipFuncSetAttribute((const void*)qk_gemm,
            hipFuncAttributeMaxDynamicSharedMemorySize, 131072);
    (void)hipFuncSetAttribute((const void*)pv_gemm,
            hipFuncAttributeMaxDynamicSharedMemorySize, 98304);

    convert_to_bf16<<<5632, 256, 0, stream>>>(x, wq, wk, wv, xb, wqb, wkb, wvb);
    qkv_gemm<<<384, 512, 131072, stream>>>(xb, wqb, wkb, wvb, Qb, Kb, Vt);
    qk_gemm<<<dim3(36, NB), 512, 131072, stream>>>(Qb, Kb, Sc);
    softmax_rows<<<dim3(SLEN, NB), 256, 0, stream>>>(Sc);
    pv_gemm<<<dim3(8, 8, NB), 512, 98304, stream>>>((const bf16*)Sc, Vt, out);
}

// Round 15
// 153.432 us; speedup vs baseline: 1.5372x; 1.0673x over previous
//
#include <hip/hip_runtime.h>
#include <hip/hip_bf16.h>
#include <stdint.h>

typedef __hip_bfloat16 bf16;
typedef __attribute__((ext_vector_type(8))) short bf16x8;
typedef __attribute__((ext_vector_type(4))) float f32x4;
typedef __attribute__((ext_vector_type(8))) unsigned short u16x8;
typedef __attribute__((ext_vector_type(4))) unsigned short u16x4;

#define SLEN 2048
#define ED   1024
#define NB   4
#define AS1 __attribute__((address_space(1)))
#define AS3 __attribute__((address_space(3)))
#define SB0() __builtin_amdgcn_sched_barrier(0)

static __device__ __forceinline__ unsigned short f2bf(float f) {
    return __builtin_bit_cast(unsigned short, __float2bfloat16(f));
}

// ============================================================================
// gemm8p (MEASURED PASSING R14, used for qk): 8-phase 256x256 / BK=64 /
// 512 thr, 8 waves (2M x 4N). See R14 ledger comments. DO NOT MODIFY.
// ============================================================================
__device__ __forceinline__ void gemm8p(
    const char* __restrict__ aT, int lda,
    const char* __restrict__ bT, int ldb,
    int nkt, char* sm, int tid, f32x4 (&acc)[8][4])
{
    const int lane = tid & 63, wave = tid >> 6;
    const int wm = wave >> 2, wn = wave & 3;
    const int fr = lane & 15, kc = lane >> 4;

    auto SU = [&](int isB, int kh, int Tn) {
        char* dst = sm + (Tn & 1) * 65536 + isB * 32768 + kh * 16384;
        const char* g = isB ? bT : aT;
        const int ld = isB ? ldb : lda;
#pragma unroll
        for (int j = 0; j < 2; ++j) {
            int rid = j * 512 + tid;
            int row = rid >> 2, c = rid & 3;
            const char* src = g + (size_t)row * ld + Tn * 128 + kh * 64
                            + ((c ^ ((row >> 1) & 3)) * 16);
            __builtin_amdgcn_global_load_lds(
                (const AS1 uint32_t*)src,
                (AS3 uint32_t*)(dst + (j * 512 + wave * 64) * 16), 16, 0, 0);
        }
    };
    auto RDA = [&](int T, int kh, bf16x8 (&a)[8]) {
        const char* pa = sm + (T & 1) * 65536 + kh * 16384;
#pragma unroll
        for (int i = 0; i < 8; ++i) {
            int row = wm * 128 + i * 16 + fr;
            a[i] = *(const bf16x8*)(pa + row * 64 + ((kc ^ ((row >> 1) & 3)) * 16));
        }
    };
    auto RDB = [&](int T, int kh, int nh, bf16x8 (&b)[2]) {
        const char* pb = sm + (T & 1) * 65536 + 32768 + kh * 16384;
#pragma unroll
        for (int n = 0; n < 2; ++n) {
            int row = wn * 64 + nh * 32 + n * 16 + fr;
            b[n] = *(const bf16x8*)(pb + row * 64 + ((kc ^ ((row >> 1) & 3)) * 16));
        }
    };
    auto MM = [&](bf16x8 (&a)[8], bf16x8 (&b)[2], int nh) {
        __builtin_amdgcn_s_setprio(1);
#pragma unroll
        for (int i = 0; i < 8; ++i)
#pragma unroll
            for (int n = 0; n < 2; ++n)
                acc[i][nh * 2 + n] = __builtin_amdgcn_mfma_f32_16x16x32_bf16(
                    a[i], b[n], acc[i][nh * 2 + n], 0, 0, 0);
        __builtin_amdgcn_s_setprio(0);
    };

    SU(0, 0, 0); SU(1, 0, 0); SU(0, 1, 0); SU(1, 1, 0);
    SU(0, 0, 1); SU(1, 0, 1); SU(0, 1, 1);
    asm volatile("s_waitcnt vmcnt(6)" ::: "memory");
    SB0();
    __builtin_amdgcn_s_barrier();

    for (int T = 0; T < nkt; ++T) {
        const bool p1 = (T + 1 < nkt), p2 = (T + 2 < nkt);
        bf16x8 a[8], b[2];
        RDA(T, 0, a); RDB(T, 0, 0, b);
        if (p1) SU(1, 1, T + 1);
        SB0(); __builtin_amdgcn_s_barrier();
        asm volatile("s_waitcnt lgkmcnt(0)" ::: "memory");
        SB0();
        MM(a, b, 0);
        SB0(); __builtin_amdgcn_s_barrier();
        RDB(T, 0, 1, b);
        if (p2) SU(0, 0, T + 2);
        SB0(); __builtin_amdgcn_s_barrier();
        asm volatile("s_waitcnt lgkmcnt(0)" ::: "memory");
        SB0();
        MM(a, b, 1);
        SB0(); __builtin_amdgcn_s_barrier();
        RDA(T, 1, a); RDB(T, 1, 0, b);
        if (p2) SU(1, 0, T + 2);
        SB0(); __builtin_amdgcn_s_barrier();
        asm volatile("s_waitcnt lgkmcnt(0)" ::: "memory");
        SB0();
        MM(a, b, 0);
        SB0(); __builtin_amdgcn_s_barrier();
        RDB(T, 1, 1, b);
        if (p2) SU(0, 1, T + 2);
        if (T < nkt - 2) asm volatile("s_waitcnt vmcnt(6)" ::: "memory");
        else             asm volatile("s_waitcnt vmcnt(0)" ::: "memory");
        SB0(); __builtin_amdgcn_s_barrier();
        asm volatile("s_waitcnt lgkmcnt(0)" ::: "memory");
        SB0();
        MM(a, b, 1);
        SB0(); __builtin_amdgcn_s_barrier();
    }
}

// ============================================================================
// gemm_core8 (MEASURED PASSING R7): 256x128 / 512 thr, 8 waves, 2-bank reg
// fragment pipelining, 96KB LDS. Used by qkv and pv. DO NOT MODIFY.
// ============================================================================
__device__ __forceinline__ void gemm_core8(
    const char* __restrict__ aT, int lda,
    const char* __restrict__ bT, int ldb,
    int nkt, char* sm, int tid, f32x4 (&acc)[4][4])
{
    const int lane = tid & 63, wave = tid >> 6;
    const int wm = wave >> 1, wn = wave & 1;
    const int fr = lane & 15, kc = lane >> 4;

    auto STAGE = [&](int kh, int Tn) {
        char* buf = sm + (Tn & 1) * 49152;
#pragma unroll
        for (int j = 0; j < 2; ++j) {
            int rid = j * 512 + tid;
            int row = rid >> 2, c = rid & 3;
            const char* src = aT + (size_t)row * lda + Tn * 128 + kh * 64
                            + ((c ^ ((row >> 1) & 3)) * 16);
            __builtin_amdgcn_global_load_lds(
                (const AS1 uint32_t*)src,
                (AS3 uint32_t*)(buf + kh * 16384 + (j * 512 + wave * 64) * 16),
                16, 0, 0);
        }
        {
            int row = tid >> 2, c = tid & 3;
            const char* src = bT + (size_t)row * ldb + Tn * 128 + kh * 64
                            + ((c ^ ((row >> 1) & 3)) * 16);
            __builtin_amdgcn_global_load_lds(
                (const AS1 uint32_t*)src,
                (AS3 uint32_t*)(buf + 32768 + kh * 8192 + (wave * 64) * 16),
                16, 0, 0);
        }
    };
    auto RD = [&](int T, int kh, bf16x8 (&a)[4], bf16x8 (&b)[4]) {
        const char* buf = sm + (T & 1) * 49152;
#pragma unroll
        for (int i = 0; i < 4; ++i) {
            int row = wm * 64 + i * 16 + fr;
            a[i] = *(const bf16x8*)(buf + kh * 16384 + row * 64
                                    + ((kc ^ ((row >> 1) & 3)) * 16));
        }
#pragma unroll
        for (int i = 0; i < 4; ++i) {
            int row = wn * 64 + i * 16 + fr;
            b[i] = *(const bf16x8*)(buf + 32768 + kh * 8192 + row * 64
                                    + ((kc ^ ((row >> 1) & 3)) * 16));
        }
    };
    auto MM = [&](bf16x8 (&a)[4], bf16x8 (&b)[4]) {
        __builtin_amdgcn_s_setprio(1);
#pragma unroll
        for (int i = 0; i < 4; ++i)
#pragma unroll
            for (int n = 0; n < 4; ++n)
                acc[i][n] = __builtin_amdgcn_mfma_f32_16x16x32_bf16(
                    a[i], b[n], acc[i][n], 0, 0, 0);
        __builtin_amdgcn_s_setprio(0);
    };

    STAGE(0, 0); STAGE(1, 0);
    asm volatile("s_waitcnt vmcnt(3)" ::: "memory");
    SB0();
    __builtin_amdgcn_s_barrier();

    bf16x8 aE[4], bE[4], aO[4], bO[4];
    for (int T = 0; T < nkt; ++T) {
        const bool pre = (T + 1 < nkt);
        RD(T, 0, aE, bE);
        SB0();
        if (pre) STAGE(0, T + 1);
        SB0();
        if (T > 0) {
            asm volatile("s_waitcnt lgkmcnt(8)" ::: "memory");
            SB0();
            MM(aO, bO);
        }
        if (pre) asm volatile("s_waitcnt vmcnt(3)" ::: "memory");
        else     asm volatile("s_waitcnt vmcnt(0)" ::: "memory");
        SB0();
        __builtin_amdgcn_s_barrier();
        RD(T, 1, aO, bO);
        SB0();
        if (pre) STAGE(1, T + 1);
        SB0();
        asm volatile("s_waitcnt lgkmcnt(8)" ::: "memory");
        SB0();
        MM(aE, bE);
        if (pre) asm volatile("s_waitcnt vmcnt(3)" ::: "memory");
        else     asm volatile("s_waitcnt vmcnt(0)" ::: "memory");
        SB0();
        __builtin_amdgcn_s_barrier();
    }
    asm volatile("s_waitcnt lgkmcnt(0)" ::: "memory");
    SB0();
    MM(aO, bO);
}

// ---------------- convert fp32 -> bf16 (x and the 3 weights) ----------------
__global__ __launch_bounds__(256) void convert_to_bf16(
    const float* __restrict__ x, const float* __restrict__ wq,
    const float* __restrict__ wk, const float* __restrict__ wv,
    bf16* __restrict__ xb, bf16* __restrict__ wqb,
    bf16* __restrict__ wkb, bf16* __restrict__ wvb)
{
    long g = (long)blockIdx.x * 256 + threadIdx.x;
    const float* src; bf16* dst; long o;
    if (g < 1048576) { src = x; dst = xb; o = g * 8; }
    else {
        long g2 = g - 1048576;
        int w = (int)(g2 >> 17);
        o = (g2 & 131071) * 8;
        src = (w == 0) ? wq : (w == 1) ? wk : wv;
        dst = (w == 0) ? wqb : (w == 1) ? wkb : wvb;
    }
    float4 v0 = *(const float4*)(src + o);
    float4 v1 = *(const float4*)(src + o + 4);
    u16x8 r;
    r[0] = f2bf(v0.x); r[1] = f2bf(v0.y); r[2] = f2bf(v0.z); r[3] = f2bf(v0.w);
    r[4] = f2bf(v1.x); r[5] = f2bf(v1.y); r[6] = f2bf(v1.z); r[7] = f2bf(v1.w);
    *(u16x8*)(dst + o) = r;
}

// ---------------- fused QKV (R7 verbatim, 61.2us measured): 768 blocks ------
__global__ __launch_bounds__(512, 2) void qkv_gemm(
    const bf16* __restrict__ xb, const bf16* __restrict__ wqb,
    const bf16* __restrict__ wkb, const bf16* __restrict__ wvb,
    bf16* __restrict__ Qb, bf16* __restrict__ Kb, bf16* __restrict__ Vt)
{
    extern __shared__ char smem[];
    int bid = blockIdx.x, tid = threadIdx.x;
    int xcd = bid & 7, i = bid >> 3;
    int tm = (xcd << 2) | (i & 3);
    int tn = i >> 2;
    const bf16* W = (tn < 8) ? wqb : (tn < 16) ? wkb : wvb;
    int tnl = tn & 7;
    f32x4 acc[4][4] = {};
    gemm_core8((const char*)(xb + (size_t)tm * 256 * ED), ED * 2,
               (const char*)(W + (size_t)tnl * 128 * ED), ED * 2,
               16, smem, tid, acc);

    int lane = tid & 63, wave = tid >> 6, wm = wave >> 1, wn = wave & 1;
    int rl = (lane >> 4) * 4, cl = lane & 15;
    if (tn < 16) {
        bf16* C = (tn < 8) ? Qb : Kb;
#pragma unroll
        for (int mf = 0; mf < 4; ++mf)
#pragma unroll
            for (int j = 0; j < 4; ++j) {
                int r = tm * 256 + wm * 64 + mf * 16 + rl + j;
#pragma unroll
                for (int nf = 0; nf < 4; ++nf) {
                    int c = tnl * 128 + wn * 64 + nf * 16 + cl;
                    C[(size_t)r * ED + c] = __float2bfloat16(acc[mf][nf][j]);
                }
            }
    } else {
#pragma unroll
        for (int mf = 0; mf < 4; ++mf)
#pragma unroll
            for (int j = 0; j < 4; ++j) {
                int r = tm * 256 + wm * 64 + mf * 16 + rl + j;
                int bb = r >> 11, s = r & 2047;
#pragma unroll
                for (int nf = 0; nf < 4; ++nf) {
                    int d = tnl * 128 + wn * 64 + nf * 16 + cl;
                    Vt[(((size_t)bb << 10) + d) * SLEN + s] = __float2bfloat16(acc[mf][nf][j]);
                }
            }
    }
}

// ---------------- scores = Q @ K^T / 32 (R14 verbatim): 36x4 blocks, 8-phase
__global__ __launch_bounds__(512, 2) void qk_gemm(
    const bf16* __restrict__ Qb, const bf16* __restrict__ Kb, float* __restrict__ Sc)
{
    extern __shared__ char smem[];
    int t = blockIdx.x, b = blockIdx.y, tid = threadIdx.x;
    int ti = 0;
    while ((ti + 1) * (ti + 2) / 2 <= t) ++ti;   // triangular decode, ti<=7
    int tj = t - ti * (ti + 1) / 2;
    f32x4 acc[8][4] = {};
    gemm8p((const char*)(Qb + ((size_t)b * SLEN + ti * 256) * ED), ED * 2,
           (const char*)(Kb + ((size_t)b * SLEN + tj * 256) * ED), ED * 2,
           16, smem, tid, acc);

    float* Sb = Sc + (size_t)b * SLEN * SLEN;
    int lane = tid & 63, wave = tid >> 6, wm = wave >> 2, wn = wave & 3;
    int rl = (lane >> 4) * 4, cl = lane & 15;
#pragma unroll
    for (int mf = 0; mf < 8; ++mf)
#pragma unroll
        for (int j = 0; j < 4; ++j) {
            int r = ti * 256 + wm * 128 + mf * 16 + rl + j;
#pragma unroll
            for (int nf = 0; nf < 4; ++nf) {
                int c = tj * 256 + wn * 64 + nf * 16 + cl;
                Sb[(size_t)r * SLEN + c] = acc[mf][nf][j] * 0.03125f;
            }
        }
}

// ---------------- causal row softmax; P stores trimmed to kmax --------------
// pv reads P row r only for k < (floor(r/256)+1)*256 = kmax; stores beyond
// kmax are provably never read -> skipped (saves ~45% of P store traffic).
__global__ __launch_bounds__(256) void softmax_rows(float* __restrict__ Sc)
{
    int q = blockIdx.x, b = blockIdx.y, tid = threadIdx.x;
    float* row = Sc + ((size_t)b * SLEN + q) * SLEN;
    int lane = tid & 63, wave = tid >> 6;
    __shared__ float red[4];

    float vals[8];
    float lmax = -3.0e38f;
#pragma unroll
    for (int r = 0; r < 2; ++r) {
        int i4 = tid + r * 256;
        if (i4 * 4 <= q) {
            float4 v = *(const float4*)(row + i4 * 4);
            vals[r * 4 + 0] = v.x; vals[r * 4 + 1] = v.y;
            vals[r * 4 + 2] = v.z; vals[r * 4 + 3] = v.w;
#pragma unroll
            for (int e = 0; e < 4; ++e) {
                int k = i4 * 4 + e;
                if (k <= q) lmax = fmaxf(lmax, vals[r * 4 + e]);
            }
        }
    }
#pragma unroll
    for (int o = 32; o > 0; o >>= 1) lmax = fmaxf(lmax, __shfl_xor(lmax, o));
    if (lane == 0) red[wave] = lmax;
    __syncthreads();
    float m = fmaxf(fmaxf(red[0], red[1]), fmaxf(red[2], red[3]));
    __syncthreads();
    float lsum = 0.f;
#pragma unroll
    for (int r = 0; r < 2; ++r) {
        int i4 = tid + r * 256;
        if (i4 * 4 <= q)
#pragma unroll
            for (int e = 0; e < 4; ++e) {
                int k = i4 * 4 + e;
                if (k <= q) lsum += __expf(vals[r * 4 + e] - m);
            }
    }
#pragma unroll
    for (int o = 32; o > 0; o >>= 1) lsum += __shfl_xor(lsum, o);
    if (lane == 0) red[wave] = lsum;
    __syncthreads();
    float inv = 1.0f / (red[0] + red[1] + red[2] + red[3]);
    unsigned short* prow = (unsigned short*)row;
    int kmax = ((q >> 8) + 1) << 8;              // pv read bound for this row
#pragma unroll
    for (int r = 0; r < 2; ++r) {
        int i4 = tid + r * 256;
        if (i4 * 4 < kmax) {
            u16x4 o4;
#pragma unroll
            for (int e = 0; e < 4; ++e) {
                int k = i4 * 4 + e;
                float p = (k <= q) ? __expf(vals[r * 4 + e] - m) * inv : 0.0f;
                o4[e] = f2bf(p);
            }
            *(u16x4*)(prow + i4 * 4) = o4;
        }
    }
}

// ---------------- O = P @ V (R7 verbatim): 256x128 tiles, 256 blocks --------
__global__ __launch_bounds__(512, 2) void pv_gemm(
    const bf16* __restrict__ P, const bf16* __restrict__ Vt, float* __restrict__ O)
{
    extern __shared__ char smem[];
    int mq = 7 - blockIdx.x, nd = blockIdx.y, b = blockIdx.z, tid = threadIdx.x;
    f32x4 acc[4][4] = {};
    int nkt = (mq + 1) * 4;                      // causal: k < (mq+1)*256
    gemm_core8((const char*)P + ((size_t)b * SLEN + mq * 256) * 8192, 8192,
               (const char*)(Vt + ((size_t)b * ED + nd * 128) * SLEN), SLEN * 2,
               nkt, smem, tid, acc);

    int lane = tid & 63, wave = tid >> 6, wm = wave >> 1, wn = wave & 1;
    int rl = (lane >> 4) * 4, cl = lane & 15;
    float* Ob = O + (size_t)b * SLEN * ED;
#pragma unroll
    for (int mf = 0; mf < 4; ++mf)
#pragma unroll
        for (int j = 0; j < 4; ++j) {
            int r = mq * 256 + wm * 64 + mf * 16 + rl + j;
#pragma unroll
            for (int nf = 0; nf < 4; ++nf) {
                int c = nd * 128 + wn * 64 + nf * 16 + cl;
                Ob[(size_t)r * ED + c] = acc[mf][nf][j];
            }
        }
}

extern "C" void kernel_launch(void* const* d_in, const int* in_sizes, int n_in,
                              void* d_out, int out_size, void* d_ws, size_t ws_size,
                              hipStream_t stream)
{
    const float* x  = (const float*)d_in[0];
    const float* wq = (const float*)d_in[1];
    const float* wk = (const float*)d_in[2];
    const float* wv = (const float*)d_in[3];
    float* out = (float*)d_out;

    char* ws = (char*)d_ws;
    bf16* xb  = (bf16*)(ws);                       // 16 MB
    bf16* wqb = (bf16*)(ws + 16777216);            // 2 MB
    bf16* wkb = (bf16*)(ws + 18874368);            // 2 MB
    bf16* wvb = (bf16*)(ws + 20971520);            // 2 MB
    bf16* Qb  = (bf16*)(ws + 23068672);            // 16 MB
    bf16* Kb  = (bf16*)(ws + 39845888);            // 16 MB
    bf16* Vt  = (bf16*)(ws + 56623104);            // 16 MB
    float* Sc = (float*)(ws + 73400320);           // 64 MB (P bf16 aliases this)

    (void)hipFuncSetAttribute((const void*)qkv_gemm,
            hipFuncAttributeMaxDynamicSharedMemorySize, 98304);
    (void)hipFuncSetAttribute((const void*)qk_gemm,
            hipFuncAttributeMaxDynamicSharedMemorySize, 131072);
    (void)hipFuncSetAttribute((const void*)pv_gemm,
            hipFuncAttributeMaxDynamicSharedMemorySize, 98304);

    convert_to_bf16<<<5632, 256, 0, stream>>>(x, wq, wk, wv, xb, wqb, wkb, wvb);
    qkv_gemm<<<768, 512, 98304, stream>>>(xb, wqb, wkb, wvb, Qb, Kb, Vt);
    qk_gemm<<<dim3(36, NB), 512, 131072, stream>>>(Qb, Kb, Sc);
    softmax_rows<<<dim3(SLEN, NB), 256, 0, stream>>>(Sc);
    pv_gemm<<<dim3(8, 8, NB), 512, 98304, stream>>>((const bf16*)Sc, Vt, out);
}